// Round 23
// baseline (123.741 us; speedup 1.0000x reference)
//
#include <hip/hip_runtime.h>
#include <stdint.h>

// x: (8,128,16,16) f32 ; codebook: (4,4096,32) f32 ; temperature: (4,1,1,1)
// row = (n*4+m)*256 + hw, 8192 rows, K=4096, D=32
// outputs (flat f32): sample[33554432] code[8192] one_hot[33554432] logit[33554432]
//
// ROUND 20 (4th submit; three infra failures) = R19 (123.0us) + ONE change:
// LDS diet 47.2KB -> 37.1KB (bf16 planes unpadded stride-32; manual smem
// partition; argmax scratch overlays) to allow 4 blocks/CU instead of 3.
// Bank conflicts on fragment reads are irrelevant at 10 b128 reads/thread.
// No launch-bounds cap (R15 lesson).

typedef short bf16x8 __attribute__((ext_vector_type(8)));
typedef float f32x4  __attribute__((ext_vector_type(4)));

__device__ __forceinline__ uint32_t rotl32(uint32_t x, uint32_t r){
  return (x << r) | (x >> (32u - r));
}

// JAX threefry2x32, key (0,42), partitionable scheme. Bits VALIDATED bit-exact
// (R2,4,6..); fast-log path VALIDATED (R11,R12,R13,R17,R18,R19).
__device__ __forceinline__ float gumbel_from_e(uint32_t e){
  uint32_t x0 = 0u, x1 = e;
  const uint32_t ks0 = 0u, ks1 = 42u, ks2 = 0x1BD11BF0u;
  x0 += ks0; x1 += ks1;
#define TFR4(a,b,c,d2) \
  x0 += x1; x1 = rotl32(x1,(a)); x1 ^= x0; \
  x0 += x1; x1 = rotl32(x1,(b)); x1 ^= x0; \
  x0 += x1; x1 = rotl32(x1,(c)); x1 ^= x0; \
  x0 += x1; x1 = rotl32(x1,(d2)); x1 ^= x0;
  TFR4(13,15,26,6)  x0 += ks1; x1 += ks2 + 1u;
  TFR4(17,29,16,24) x0 += ks2; x1 += ks0 + 2u;
  TFR4(13,15,26,6)  x0 += ks0; x1 += ks1 + 3u;
  TFR4(17,29,16,24) x0 += ks1; x1 += ks2 + 4u;
  TFR4(13,15,26,6)  x0 += ks2; x1 += ks0 + 5u;
#undef TFR4
  uint32_t bits = x0 ^ x1;
  float u = __uint_as_float((bits >> 9) | 0x3F800000u) - 1.0f;
  u = fminf(fmaxf(u, 1.1920929e-07f), __uint_as_float(0x3F7FFFFEu));
  const float LN2 = 0.69314718055994531f;
  float v = -LN2 * __log2f(u);
  return -LN2 * __log2f(v);
}

// Truncating bf16 split: v ~= hi + lo, |v-(hi+lo)| <= 2^-16 |v|.
__device__ __forceinline__ void split_bf16(float v, unsigned short& hi, unsigned short& lo){
  uint32_t b = __float_as_uint(v);
  hi = (unsigned short)(b >> 16);
  float r = v - __uint_as_float(b & 0xFFFF0000u);
  lo = (unsigned short)(__float_as_uint(r) >> 16);
}

// Kernel 1: grid 4096 = m(4) x rowtile(64) x ktile(16); block 512 thr (8 waves),
// 32 rows x 256 k. bf16x3 MFMA GEMM (R17 layouts), ws partials (R18),
// interleaved zero-fill (R19). LDS: manual partition, 38016 B total.
template<bool USE_WS>
__global__ __launch_bounds__(512) void k_logits(
    const float* __restrict__ x, const float* __restrict__ cb,
    const float* __restrict__ temp, float* __restrict__ logit_out,
    float* __restrict__ sample, float* __restrict__ onehot,
    float* __restrict__ part_ws){
  __shared__ __align__(16) char smem[38016];
  unsigned short* cbh = (unsigned short*)smem;        // 256x32 bf16 hi   [0,16384)
  unsigned short* cbl = cbh + 8192;                   // 256x32 bf16 lo   [16384,32768)
  unsigned short* xbh = cbl + 8192;                   // 32x32 bf16 hi    [32768,34816)
  unsigned short* xbl = xbh + 1024;                   // 32x32 bf16 lo    [34816,36864)
  float* c2l = (float*)(xbl + 1024);                  // 256 f32          [36864,37888)
  float* x2l = c2l + 256;                             // 32 f32           [37888,38016)
  float* red = (float*)smem;                          // argmax scratch overlays 33280 B

  const int tid = threadIdx.x;
  const int b = blockIdx.x;
  const int kt = b & 15;
  const int rt = (b >> 4) & 63;
  const int m  = b >> 10;
  const int n  = rt >> 3;
  const int hw0 = (rt & 7) << 5;
  const int k0 = kt << 8;
  const int rowbase = ((n << 2) + m) * 256 + hw0;

  // ---- stage x tile (32 rows x 32 d) as bf16 hi/lo planes ----
  const float* xm = x + ((n * 128 + m * 32) * 256 + hw0);
  #pragma unroll
  for (int i = 0; i < 2; ++i){
    int idx = tid + (i << 9);
    int d = idx >> 5, r = idx & 31;
    float v = xm[(d << 8) + r];
    unsigned short h, l;
    split_bf16(v, h, l);
    xbh[(r << 5) + d] = h;
    xbl[(r << 5) + d] = l;
  }
  // ---- stage codebook tile: bf16 hi/lo + shuffle-tree c2 ----
  const float4* cb4 = (const float4*)(cb + (m * 131072 + k0 * 32));
  #pragma unroll
  for (int i = 0; i < 4; ++i){
    int f = tid + (i << 9);
    float4 v = cb4[f];
    int kk = f >> 3, dq = f & 7;
    unsigned short h0,h1,h2,h3,l0,l1,l2,l3;
    split_bf16(v.x, h0, l0); split_bf16(v.y, h1, l1);
    split_bf16(v.z, h2, l2); split_bf16(v.w, h3, l3);
    uint2 hw_, lw_;
    hw_.x = (uint32_t)h0 | ((uint32_t)h1 << 16);
    hw_.y = (uint32_t)h2 | ((uint32_t)h3 << 16);
    lw_.x = (uint32_t)l0 | ((uint32_t)l1 << 16);
    lw_.y = (uint32_t)l2 | ((uint32_t)l3 << 16);
    *(uint2*)&cbh[(kk << 5) + (dq << 2)] = hw_;
    *(uint2*)&cbl[(kk << 5) + (dq << 2)] = lw_;
    float p = fmaf(v.x, v.x, fmaf(v.y, v.y, fmaf(v.z, v.z, v.w * v.w)));
    p += __shfl_xor(p, 1);
    p += __shfl_xor(p, 2);
    p += __shfl_xor(p, 4);
    if (dq == 0) c2l[kk] = p;
  }
  __syncthreads();

  // ---- x2 from recombined planes (consistent with MFMA's x-tilde) ----
  if (tid < 32){
    float s = 0.f;
    #pragma unroll
    for (int d = 0; d < 32; ++d){
      float vh = __uint_as_float(((uint32_t)xbh[(tid << 5) + d]) << 16);
      float vl = __uint_as_float(((uint32_t)xbl[(tid << 5) + d]) << 16);
      float v = vh + vl;
      s = fmaf(v, v, s);
    }
    x2l[tid] = s;
  }
  __syncthreads();

  const int lane = tid & 63;
  const int w    = tid >> 6;
  const int mh   = w >> 2;
  const int ng   = w & 3;
  const int l15  = lane & 15;
  const int kgrp = lane >> 4;

  bf16x8 Ah = *(const bf16x8*)&xbh[((mh * 16 + l15) << 5) + (kgrp << 3)];
  bf16x8 Al = *(const bf16x8*)&xbl[((mh * 16 + l15) << 5) + (kgrp << 3)];

  float x2r[4];
  #pragma unroll
  for (int j = 0; j < 4; ++j) x2r[j] = x2l[mh * 16 + (kgrp << 2) + j];

  const float tcl = fmaxf(temp[m], 1e-6f);
  const float4 z4 = make_float4(0.f, 0.f, 0.f, 0.f);
  float bl[4], bg[4]; int bli[4], bgi[4];
  #pragma unroll
  for (int j = 0; j < 4; ++j){ bl[j] = -INFINITY; bg[j] = -INFINITY; bli[j] = 0; bgi[j] = 0; }

  #pragma unroll
  for (int t = 0; t < 4; ++t){
    const int nt = (ng << 2) + t;
    const int k_blk = (nt << 4) + l15;
    bf16x8 Bh = *(const bf16x8*)&cbh[(k_blk << 5) + (kgrp << 3)];
    bf16x8 Bl = *(const bf16x8*)&cbl[(k_blk << 5) + (kgrp << 3)];
    f32x4 acc = {0.f, 0.f, 0.f, 0.f};
    acc = __builtin_amdgcn_mfma_f32_16x16x32_bf16(Ah, Bh, acc, 0, 0, 0);
    acc = __builtin_amdgcn_mfma_f32_16x16x32_bf16(Ah, Bl, acc, 0, 0, 0);
    acc = __builtin_amdgcn_mfma_f32_16x16x32_bf16(Al, Bh, acc, 0, 0, 0);

    const float c2 = c2l[k_blk];
    const int k_g = k0 + k_blk;
    #pragma unroll
    for (int j = 0; j < 4; ++j){
      const int r_blk = mh * 16 + (kgrp << 2) + j;   // D: col=lane&15, row=(lane>>4)*4+reg
      const int row_g = rowbase + r_blk;
      float dist = x2r[j] + c2 - 2.0f * acc[j];
      float lgt = (-dist) * 0.015625f * tcl;
      logit_out[((size_t)row_g << 12) + k_g] = lgt;
      float lg = lgt + gumbel_from_e(((uint32_t)row_g << 12) + (uint32_t)k_g);
      if (lgt > bl[j]) { bl[j] = lgt; bli[j] = k_g; }
      if (lg  > bg[j]) { bg[j] = lg;  bgi[j] = k_g; }
    }

    if (USE_WS){
      // interleaved zero-fill slice t (paced by the 16 gumbels above)
      int s = tid + (t << 9);
      int r2 = s >> 6, w4 = s & 63;
      size_t f4 = (((size_t)(rowbase + r2)) << 10) + (k0 >> 2) + w4;
      ((float4*)onehot)[f4] = z4;
      ((float4*)sample)[f4] = z4;
    }
  }

  // ---- two-stage LDS argmax reduction (red overlays cbh/cbl/xb*; c2l/x2l dead) ----
  __syncthreads();
  #pragma unroll
  for (int j = 0; j < 4; ++j){
    int row = mh * 16 + (kgrp << 2) + j;
    int slot = (ng << 4) + l15;
    red[        row * 65 + slot] = bl[j];
    red[2080 +  row * 65 + slot] = __int_as_float(bli[j]);
    red[4160 +  row * 65 + slot] = bg[j];
    red[6240 +  row * 65 + slot] = __int_as_float(bgi[j]);
  }
  __syncthreads();
  if (tid < 64){
    const int r = tid & 31;
    const bool doG = (tid >= 32);
    const int off_v = doG ? 4160 : 0;
    const int off_i = doG ? 6240 : 2080;
    float bv = -INFINITY; int bi = 0;
    for (int g2 = 0; g2 < 64; ++g2){
      float v = red[off_v + r * 65 + g2];
      int  ix = __float_as_int(red[off_i + r * 65 + g2]);
      if (v > bv || (v == bv && ix < bi)){ bv = v; bi = ix; }
    }
    const int row_g = rowbase + r;
    if (USE_WS){
      *(float2*)&part_ws[((size_t)row_g << 6) + (kt << 2) + (doG ? 2 : 0)]
          = make_float2(bv, __int_as_float(bi));
    } else {
      float* part = sample + ((size_t)row_g << 12);
      part[(doG ? 32 : 0)  + kt] = bv;
      part[(doG ? 48 : 16) + kt] = __int_as_float(bi);
    }
  }

  if (!USE_WS){
    // fallback: R18-validated tail fill
    #pragma unroll
    for (int i2 = 0; i2 < 4; ++i2){
      int s = tid + (i2 << 9);
      int r = s >> 6, w4 = s & 63;
      size_t f4 = (((size_t)(rowbase + r)) << 10) + (k0 >> 2) + w4;
      ((float4*)onehot)[f4] = z4;
      if (!(kt == 0 && w4 < 16))
        ((float4*)sample)[f4] = z4;
    }
  }
}

// Kernel 2: one wave per row (2048 blocks x 256). Reduce 16 partials, scatter.
template<bool USE_WS>
__global__ __launch_bounds__(256) void k_finalize(
    float* __restrict__ sample, float* __restrict__ code_out,
    float* __restrict__ onehot, const float* __restrict__ part_ws){
  const int tid = threadIdx.x;
  const int row = (blockIdx.x << 2) + (tid >> 6);
  const int lane = tid & 63;
  float* srow = sample + ((size_t)row << 12);
  float* orow = onehot + ((size_t)row << 12);

  const int g = (lane >> 4) & 1;
  const int l16 = lane & 15;
  float v; int ix;
  if (lane < 32){
    if (USE_WS){
      float2 p2 = *(const float2*)&part_ws[((size_t)row << 6) + (l16 << 2) + (g ? 2 : 0)];
      v = p2.x; ix = __float_as_int(p2.y);
    } else {
      v  = srow[g * 32 + l16];
      ix = __float_as_int(srow[g * 32 + 16 + l16]);
    }
  } else { v = -INFINITY; ix = 0x7fffffff; }
  #pragma unroll
  for (int off = 1; off < 16; off <<= 1){
    float ov = __shfl_xor(v, off, 16);
    int   oi = __shfl_xor(ix, off, 16);
    if (ov > v || (ov == v && oi < ix)){ v = ov; ix = oi; }
  }
  const int codei = __shfl(ix, 0, 64);   // L winner
  const int hard  = __shfl(ix, 16, 64);  // G winner

  if (USE_WS){
    if (lane == 0)      srow[hard]  = 1.0f;
    else if (lane == 1) orow[codei] = 1.0f;
    else if (lane == 2) code_out[row] = (float)codei;
  } else {
    if (lane < 16){
      float4 vs = make_float4(0.f, 0.f, 0.f, 0.f);
      if ((hard >> 2) == lane) ((float*)&vs)[hard & 3] = 1.0f;
      ((float4*)srow)[lane] = vs;
    } else if (lane == 16){
      if (hard >= 64) srow[hard] = 1.0f;
    } else if (lane == 17){
      orow[codei] = 1.0f;
    } else if (lane == 18){
      code_out[row] = (float)codei;
    }
  }
}

extern "C" void kernel_launch(void* const* d_in, const int* in_sizes, int n_in,
                              void* d_out, int out_size, void* d_ws, size_t ws_size,
                              hipStream_t stream) {
  const float* x    = (const float*)d_in[0];
  const float* cb   = (const float*)d_in[1];
  const float* temp = (const float*)d_in[2];
  float* out    = (float*)d_out;
  float* sample = out;                       // 33554432
  float* code   = out + 33554432;            // 8192
  float* onehot = code + 8192;               // 33554432
  float* logit  = onehot + 33554432;         // 33554432
  float* ws     = (float*)d_ws;

  const bool use_ws = ws_size >= (size_t)8192 * 64 * sizeof(float);
  if (use_ws){
    hipLaunchKernelGGL((k_logits<true>), dim3(4096), dim3(512), 0, stream,
                       x, cb, temp, logit, sample, onehot, ws);
    hipLaunchKernelGGL((k_finalize<true>), dim3(2048), dim3(256), 0, stream,
                       sample, code, onehot, ws);
  } else {
    hipLaunchKernelGGL((k_logits<false>), dim3(4096), dim3(512), 0, stream,
                       x, cb, temp, logit, sample, onehot, ws);
    hipLaunchKernelGGL((k_finalize<false>), dim3(2048), dim3(256), 0, stream,
                       sample, code, onehot, ws);
  }
}

// Round 24
// 119.086 us; speedup vs baseline: 1.0391x; 1.0391x over previous
//
#include <hip/hip_runtime.h>
#include <stdint.h>

// x: (8,128,16,16) f32 ; codebook: (4,4096,32) f32 ; temperature: (4,1,1,1)
// row = (n*4+m)*256 + hw, 8192 rows, K=4096, D=32
// outputs (flat f32): sample[33554432] code[8192] one_hot[33554432] logit[33554432]
//
// ROUND 24 = R23 (123.7us) + ONE change: __launch_bounds__(512, 8) on
// k_logits -> VGPR capped at 64 -> 8 waves/SIMD (4 blocks/CU; the R23 LDS
// diet to 38KB is the enabler). R23's null LDS-diet implies VGPR (65-128
// band = 4 waves/SIMD per m69's measured steps) was the binding limit.
// R15's spill disaster had ~90+ live regs (fp32 acc[4][4] + fill state);
// this kernel's steady live set is ~50-60 -> clean 64-reg alloc plausible.
// Spill signature if wrong: GB-scale FETCH + dur>250us -> revert.

typedef short bf16x8 __attribute__((ext_vector_type(8)));
typedef float f32x4  __attribute__((ext_vector_type(4)));

__device__ __forceinline__ uint32_t rotl32(uint32_t x, uint32_t r){
  return (x << r) | (x >> (32u - r));
}

// JAX threefry2x32, key (0,42), partitionable scheme. Bits VALIDATED bit-exact
// (R2,4,6..); fast-log path VALIDATED (R11,R12,R13,R17,R18,R19,R23).
__device__ __forceinline__ float gumbel_from_e(uint32_t e){
  uint32_t x0 = 0u, x1 = e;
  const uint32_t ks0 = 0u, ks1 = 42u, ks2 = 0x1BD11BF0u;
  x0 += ks0; x1 += ks1;
#define TFR4(a,b,c,d2) \
  x0 += x1; x1 = rotl32(x1,(a)); x1 ^= x0; \
  x0 += x1; x1 = rotl32(x1,(b)); x1 ^= x0; \
  x0 += x1; x1 = rotl32(x1,(c)); x1 ^= x0; \
  x0 += x1; x1 = rotl32(x1,(d2)); x1 ^= x0;
  TFR4(13,15,26,6)  x0 += ks1; x1 += ks2 + 1u;
  TFR4(17,29,16,24) x0 += ks2; x1 += ks0 + 2u;
  TFR4(13,15,26,6)  x0 += ks0; x1 += ks1 + 3u;
  TFR4(17,29,16,24) x0 += ks1; x1 += ks2 + 4u;
  TFR4(13,15,26,6)  x0 += ks2; x1 += ks0 + 5u;
#undef TFR4
  uint32_t bits = x0 ^ x1;
  float u = __uint_as_float((bits >> 9) | 0x3F800000u) - 1.0f;
  u = fminf(fmaxf(u, 1.1920929e-07f), __uint_as_float(0x3F7FFFFEu));
  const float LN2 = 0.69314718055994531f;
  float v = -LN2 * __log2f(u);
  return -LN2 * __log2f(v);
}

// Truncating bf16 split: v ~= hi + lo, |v-(hi+lo)| <= 2^-16 |v|.
__device__ __forceinline__ void split_bf16(float v, unsigned short& hi, unsigned short& lo){
  uint32_t b = __float_as_uint(v);
  hi = (unsigned short)(b >> 16);
  float r = v - __uint_as_float(b & 0xFFFF0000u);
  lo = (unsigned short)(__float_as_uint(r) >> 16);
}

// Kernel 1: grid 4096 = m(4) x rowtile(64) x ktile(16); block 512 thr (8 waves),
// 32 rows x 256 k. bf16x3 MFMA GEMM (R17 layouts), ws partials (R18),
// interleaved zero-fill (R19), 38KB LDS (R23). VGPR capped to 64.
template<bool USE_WS>
__global__ __launch_bounds__(512, 8) void k_logits(
    const float* __restrict__ x, const float* __restrict__ cb,
    const float* __restrict__ temp, float* __restrict__ logit_out,
    float* __restrict__ sample, float* __restrict__ onehot,
    float* __restrict__ part_ws){
  __shared__ __align__(16) char smem[38016];
  unsigned short* cbh = (unsigned short*)smem;        // 256x32 bf16 hi   [0,16384)
  unsigned short* cbl = cbh + 8192;                   // 256x32 bf16 lo   [16384,32768)
  unsigned short* xbh = cbl + 8192;                   // 32x32 bf16 hi    [32768,34816)
  unsigned short* xbl = xbh + 1024;                   // 32x32 bf16 lo    [34816,36864)
  float* c2l = (float*)(xbl + 1024);                  // 256 f32          [36864,37888)
  float* x2l = c2l + 256;                             // 32 f32           [37888,38016)
  float* red = (float*)smem;                          // argmax scratch overlays 33280 B

  const int tid = threadIdx.x;
  const int b = blockIdx.x;
  const int kt = b & 15;
  const int rt = (b >> 4) & 63;
  const int m  = b >> 10;
  const int n  = rt >> 3;
  const int hw0 = (rt & 7) << 5;
  const int k0 = kt << 8;
  const int rowbase = ((n << 2) + m) * 256 + hw0;

  // ---- stage x tile (32 rows x 32 d) as bf16 hi/lo planes ----
  const float* xm = x + ((n * 128 + m * 32) * 256 + hw0);
  #pragma unroll
  for (int i = 0; i < 2; ++i){
    int idx = tid + (i << 9);
    int d = idx >> 5, r = idx & 31;
    float v = xm[(d << 8) + r];
    unsigned short h, l;
    split_bf16(v, h, l);
    xbh[(r << 5) + d] = h;
    xbl[(r << 5) + d] = l;
  }
  // ---- stage codebook tile: bf16 hi/lo + shuffle-tree c2 ----
  const float4* cb4 = (const float4*)(cb + (m * 131072 + k0 * 32));
  #pragma unroll
  for (int i = 0; i < 4; ++i){
    int f = tid + (i << 9);
    float4 v = cb4[f];
    int kk = f >> 3, dq = f & 7;
    unsigned short h0,h1,h2,h3,l0,l1,l2,l3;
    split_bf16(v.x, h0, l0); split_bf16(v.y, h1, l1);
    split_bf16(v.z, h2, l2); split_bf16(v.w, h3, l3);
    uint2 hw_, lw_;
    hw_.x = (uint32_t)h0 | ((uint32_t)h1 << 16);
    hw_.y = (uint32_t)h2 | ((uint32_t)h3 << 16);
    lw_.x = (uint32_t)l0 | ((uint32_t)l1 << 16);
    lw_.y = (uint32_t)l2 | ((uint32_t)l3 << 16);
    *(uint2*)&cbh[(kk << 5) + (dq << 2)] = hw_;
    *(uint2*)&cbl[(kk << 5) + (dq << 2)] = lw_;
    float p = fmaf(v.x, v.x, fmaf(v.y, v.y, fmaf(v.z, v.z, v.w * v.w)));
    p += __shfl_xor(p, 1);
    p += __shfl_xor(p, 2);
    p += __shfl_xor(p, 4);
    if (dq == 0) c2l[kk] = p;
  }
  __syncthreads();

  // ---- x2 from recombined planes (consistent with MFMA's x-tilde) ----
  if (tid < 32){
    float s = 0.f;
    #pragma unroll
    for (int d = 0; d < 32; ++d){
      float vh = __uint_as_float(((uint32_t)xbh[(tid << 5) + d]) << 16);
      float vl = __uint_as_float(((uint32_t)xbl[(tid << 5) + d]) << 16);
      float v = vh + vl;
      s = fmaf(v, v, s);
    }
    x2l[tid] = s;
  }
  __syncthreads();

  const int lane = tid & 63;
  const int w    = tid >> 6;
  const int mh   = w >> 2;
  const int ng   = w & 3;
  const int l15  = lane & 15;
  const int kgrp = lane >> 4;

  bf16x8 Ah = *(const bf16x8*)&xbh[((mh * 16 + l15) << 5) + (kgrp << 3)];
  bf16x8 Al = *(const bf16x8*)&xbl[((mh * 16 + l15) << 5) + (kgrp << 3)];

  float x2r[4];
  #pragma unroll
  for (int j = 0; j < 4; ++j) x2r[j] = x2l[mh * 16 + (kgrp << 2) + j];

  const float tcl = fmaxf(temp[m], 1e-6f);
  const float4 z4 = make_float4(0.f, 0.f, 0.f, 0.f);
  float bl[4], bg[4]; int bli[4], bgi[4];
  #pragma unroll
  for (int j = 0; j < 4; ++j){ bl[j] = -INFINITY; bg[j] = -INFINITY; bli[j] = 0; bgi[j] = 0; }

  #pragma unroll
  for (int t = 0; t < 4; ++t){
    const int nt = (ng << 2) + t;
    const int k_blk = (nt << 4) + l15;
    bf16x8 Bh = *(const bf16x8*)&cbh[(k_blk << 5) + (kgrp << 3)];
    bf16x8 Bl = *(const bf16x8*)&cbl[(k_blk << 5) + (kgrp << 3)];
    f32x4 acc = {0.f, 0.f, 0.f, 0.f};
    acc = __builtin_amdgcn_mfma_f32_16x16x32_bf16(Ah, Bh, acc, 0, 0, 0);
    acc = __builtin_amdgcn_mfma_f32_16x16x32_bf16(Ah, Bl, acc, 0, 0, 0);
    acc = __builtin_amdgcn_mfma_f32_16x16x32_bf16(Al, Bh, acc, 0, 0, 0);

    const float c2 = c2l[k_blk];
    const int k_g = k0 + k_blk;
    #pragma unroll
    for (int j = 0; j < 4; ++j){
      const int r_blk = mh * 16 + (kgrp << 2) + j;   // D: col=lane&15, row=(lane>>4)*4+reg
      const int row_g = rowbase + r_blk;
      float dist = x2r[j] + c2 - 2.0f * acc[j];
      float lgt = (-dist) * 0.015625f * tcl;
      logit_out[((size_t)row_g << 12) + k_g] = lgt;
      float lg = lgt + gumbel_from_e(((uint32_t)row_g << 12) + (uint32_t)k_g);
      if (lgt > bl[j]) { bl[j] = lgt; bli[j] = k_g; }
      if (lg  > bg[j]) { bg[j] = lg;  bgi[j] = k_g; }
    }

    if (USE_WS){
      // interleaved zero-fill slice t (paced by the 16 gumbels above)
      int s = tid + (t << 9);
      int r2 = s >> 6, w4 = s & 63;
      size_t f4 = (((size_t)(rowbase + r2)) << 10) + (k0 >> 2) + w4;
      ((float4*)onehot)[f4] = z4;
      ((float4*)sample)[f4] = z4;
    }
  }

  // ---- two-stage LDS argmax reduction (red overlays cbh/cbl/xb*; c2l/x2l dead) ----
  __syncthreads();
  #pragma unroll
  for (int j = 0; j < 4; ++j){
    int row = mh * 16 + (kgrp << 2) + j;
    int slot = (ng << 4) + l15;
    red[        row * 65 + slot] = bl[j];
    red[2080 +  row * 65 + slot] = __int_as_float(bli[j]);
    red[4160 +  row * 65 + slot] = bg[j];
    red[6240 +  row * 65 + slot] = __int_as_float(bgi[j]);
  }
  __syncthreads();
  if (tid < 64){
    const int r = tid & 31;
    const bool doG = (tid >= 32);
    const int off_v = doG ? 4160 : 0;
    const int off_i = doG ? 6240 : 2080;
    float bv = -INFINITY; int bi = 0;
    for (int g2 = 0; g2 < 64; ++g2){
      float v = red[off_v + r * 65 + g2];
      int  ix = __float_as_int(red[off_i + r * 65 + g2]);
      if (v > bv || (v == bv && ix < bi)){ bv = v; bi = ix; }
    }
    const int row_g = rowbase + r;
    if (USE_WS){
      *(float2*)&part_ws[((size_t)row_g << 6) + (kt << 2) + (doG ? 2 : 0)]
          = make_float2(bv, __int_as_float(bi));
    } else {
      float* part = sample + ((size_t)row_g << 12);
      part[(doG ? 32 : 0)  + kt] = bv;
      part[(doG ? 48 : 16) + kt] = __int_as_float(bi);
    }
  }

  if (!USE_WS){
    // fallback: R18-validated tail fill
    #pragma unroll
    for (int i2 = 0; i2 < 4; ++i2){
      int s = tid + (i2 << 9);
      int r = s >> 6, w4 = s & 63;
      size_t f4 = (((size_t)(rowbase + r)) << 10) + (k0 >> 2) + w4;
      ((float4*)onehot)[f4] = z4;
      if (!(kt == 0 && w4 < 16))
        ((float4*)sample)[f4] = z4;
    }
  }
}

// Kernel 2: one wave per row (2048 blocks x 256). Reduce 16 partials, scatter.
template<bool USE_WS>
__global__ __launch_bounds__(256) void k_finalize(
    float* __restrict__ sample, float* __restrict__ code_out,
    float* __restrict__ onehot, const float* __restrict__ part_ws){
  const int tid = threadIdx.x;
  const int row = (blockIdx.x << 2) + (tid >> 6);
  const int lane = tid & 63;
  float* srow = sample + ((size_t)row << 12);
  float* orow = onehot + ((size_t)row << 12);

  const int g = (lane >> 4) & 1;
  const int l16 = lane & 15;
  float v; int ix;
  if (lane < 32){
    if (USE_WS){
      float2 p2 = *(const float2*)&part_ws[((size_t)row << 6) + (l16 << 2) + (g ? 2 : 0)];
      v = p2.x; ix = __float_as_int(p2.y);
    } else {
      v  = srow[g * 32 + l16];
      ix = __float_as_int(srow[g * 32 + 16 + l16]);
    }
  } else { v = -INFINITY; ix = 0x7fffffff; }
  #pragma unroll
  for (int off = 1; off < 16; off <<= 1){
    float ov = __shfl_xor(v, off, 16);
    int   oi = __shfl_xor(ix, off, 16);
    if (ov > v || (ov == v && oi < ix)){ v = ov; ix = oi; }
  }
  const int codei = __shfl(ix, 0, 64);   // L winner
  const int hard  = __shfl(ix, 16, 64);  // G winner

  if (USE_WS){
    if (lane == 0)      srow[hard]  = 1.0f;
    else if (lane == 1) orow[codei] = 1.0f;
    else if (lane == 2) code_out[row] = (float)codei;
  } else {
    if (lane < 16){
      float4 vs = make_float4(0.f, 0.f, 0.f, 0.f);
      if ((hard >> 2) == lane) ((float*)&vs)[hard & 3] = 1.0f;
      ((float4*)srow)[lane] = vs;
    } else if (lane == 16){
      if (hard >= 64) srow[hard] = 1.0f;
    } else if (lane == 17){
      orow[codei] = 1.0f;
    } else if (lane == 18){
      code_out[row] = (float)codei;
    }
  }
}

extern "C" void kernel_launch(void* const* d_in, const int* in_sizes, int n_in,
                              void* d_out, int out_size, void* d_ws, size_t ws_size,
                              hipStream_t stream) {
  const float* x    = (const float*)d_in[0];
  const float* cb   = (const float*)d_in[1];
  const float* temp = (const float*)d_in[2];
  float* out    = (float*)d_out;
  float* sample = out;                       // 33554432
  float* code   = out + 33554432;            // 8192
  float* onehot = code + 8192;               // 33554432
  float* logit  = onehot + 33554432;         // 33554432
  float* ws     = (float*)d_ws;

  const bool use_ws = ws_size >= (size_t)8192 * 64 * sizeof(float);
  if (use_ws){
    hipLaunchKernelGGL((k_logits<true>), dim3(4096), dim3(512), 0, stream,
                       x, cb, temp, logit, sample, onehot, ws);
    hipLaunchKernelGGL((k_finalize<true>), dim3(2048), dim3(256), 0, stream,
                       sample, code, onehot, ws);
  } else {
    hipLaunchKernelGGL((k_logits<false>), dim3(4096), dim3(512), 0, stream,
                       x, cb, temp, logit, sample, onehot, ws);
    hipLaunchKernelGGL((k_finalize<false>), dim3(2048), dim3(256), 0, stream,
                       sample, code, onehot, ws);
  }
}

// Round 25
// 111.875 us; speedup vs baseline: 1.1061x; 1.0644x over previous
//
#include <hip/hip_runtime.h>
#include <stdint.h>

// x: (8,128,16,16) f32 ; codebook: (4,4096,32) f32 ; temperature: (4,1,1,1)
// row = (n*4+m)*256 + hw, 8192 rows, K=4096, D=32
// outputs (flat f32): sample[33554432] code[8192] one_hot[33554432] logit[33554432]
//
// ROUND 25 = R24 (119.1us) + ONE change: the interleaved zero-fill stores
// (268 MB, full-line float4, never re-read) become NON-TEMPORAL. Logit
// stores stay plain (4B/lane scalar -> want L2 line assembly). R10's
// NT-everywhere regression was on the fp32 VALU-bound kernel at 2 blocks/CU;
// current kernel is at 8 waves/SIMD with the write stream as the larger
// floor term (R10 measured: plain 568 MB vs NT 407 MB WRITE_SIZE).

typedef short bf16x8 __attribute__((ext_vector_type(8)));
typedef float f32x4  __attribute__((ext_vector_type(4)));
typedef float floatx4 __attribute__((ext_vector_type(4)));  // clang-native for NT builtin

__device__ __forceinline__ uint32_t rotl32(uint32_t x, uint32_t r){
  return (x << r) | (x >> (32u - r));
}

// JAX threefry2x32, key (0,42), partitionable scheme. Bits VALIDATED bit-exact
// (R2,4,6..); fast-log path VALIDATED (R11,R12,R13,R17,R18,R19,R23,R24).
__device__ __forceinline__ float gumbel_from_e(uint32_t e){
  uint32_t x0 = 0u, x1 = e;
  const uint32_t ks0 = 0u, ks1 = 42u, ks2 = 0x1BD11BF0u;
  x0 += ks0; x1 += ks1;
#define TFR4(a,b,c,d2) \
  x0 += x1; x1 = rotl32(x1,(a)); x1 ^= x0; \
  x0 += x1; x1 = rotl32(x1,(b)); x1 ^= x0; \
  x0 += x1; x1 = rotl32(x1,(c)); x1 ^= x0; \
  x0 += x1; x1 = rotl32(x1,(d2)); x1 ^= x0;
  TFR4(13,15,26,6)  x0 += ks1; x1 += ks2 + 1u;
  TFR4(17,29,16,24) x0 += ks2; x1 += ks0 + 2u;
  TFR4(13,15,26,6)  x0 += ks0; x1 += ks1 + 3u;
  TFR4(17,29,16,24) x0 += ks1; x1 += ks2 + 4u;
  TFR4(13,15,26,6)  x0 += ks2; x1 += ks0 + 5u;
#undef TFR4
  uint32_t bits = x0 ^ x1;
  float u = __uint_as_float((bits >> 9) | 0x3F800000u) - 1.0f;
  u = fminf(fmaxf(u, 1.1920929e-07f), __uint_as_float(0x3F7FFFFEu));
  const float LN2 = 0.69314718055994531f;
  float v = -LN2 * __log2f(u);
  return -LN2 * __log2f(v);
}

// Truncating bf16 split: v ~= hi + lo, |v-(hi+lo)| <= 2^-16 |v|.
__device__ __forceinline__ void split_bf16(float v, unsigned short& hi, unsigned short& lo){
  uint32_t b = __float_as_uint(v);
  hi = (unsigned short)(b >> 16);
  float r = v - __uint_as_float(b & 0xFFFF0000u);
  lo = (unsigned short)(__float_as_uint(r) >> 16);
}

// Kernel 1: grid 4096 = m(4) x rowtile(64) x ktile(16); block 512 thr (8 waves),
// 32 rows x 256 k. bf16x3 MFMA GEMM (R17 layouts), ws partials (R18),
// interleaved NT zero-fill, 38KB LDS (R23), VGPR capped to 64 (R24).
template<bool USE_WS>
__global__ __launch_bounds__(512, 8) void k_logits(
    const float* __restrict__ x, const float* __restrict__ cb,
    const float* __restrict__ temp, float* __restrict__ logit_out,
    float* __restrict__ sample, float* __restrict__ onehot,
    float* __restrict__ part_ws){
  __shared__ __align__(16) char smem[38016];
  unsigned short* cbh = (unsigned short*)smem;        // 256x32 bf16 hi   [0,16384)
  unsigned short* cbl = cbh + 8192;                   // 256x32 bf16 lo   [16384,32768)
  unsigned short* xbh = cbl + 8192;                   // 32x32 bf16 hi    [32768,34816)
  unsigned short* xbl = xbh + 1024;                   // 32x32 bf16 lo    [34816,36864)
  float* c2l = (float*)(xbl + 1024);                  // 256 f32          [36864,37888)
  float* x2l = c2l + 256;                             // 32 f32           [37888,38016)
  float* red = (float*)smem;                          // argmax scratch overlays 33280 B

  const int tid = threadIdx.x;
  const int b = blockIdx.x;
  const int kt = b & 15;
  const int rt = (b >> 4) & 63;
  const int m  = b >> 10;
  const int n  = rt >> 3;
  const int hw0 = (rt & 7) << 5;
  const int k0 = kt << 8;
  const int rowbase = ((n << 2) + m) * 256 + hw0;

  // ---- stage x tile (32 rows x 32 d) as bf16 hi/lo planes ----
  const float* xm = x + ((n * 128 + m * 32) * 256 + hw0);
  #pragma unroll
  for (int i = 0; i < 2; ++i){
    int idx = tid + (i << 9);
    int d = idx >> 5, r = idx & 31;
    float v = xm[(d << 8) + r];
    unsigned short h, l;
    split_bf16(v, h, l);
    xbh[(r << 5) + d] = h;
    xbl[(r << 5) + d] = l;
  }
  // ---- stage codebook tile: bf16 hi/lo + shuffle-tree c2 ----
  const float4* cb4 = (const float4*)(cb + (m * 131072 + k0 * 32));
  #pragma unroll
  for (int i = 0; i < 4; ++i){
    int f = tid + (i << 9);
    float4 v = cb4[f];
    int kk = f >> 3, dq = f & 7;
    unsigned short h0,h1,h2,h3,l0,l1,l2,l3;
    split_bf16(v.x, h0, l0); split_bf16(v.y, h1, l1);
    split_bf16(v.z, h2, l2); split_bf16(v.w, h3, l3);
    uint2 hw_, lw_;
    hw_.x = (uint32_t)h0 | ((uint32_t)h1 << 16);
    hw_.y = (uint32_t)h2 | ((uint32_t)h3 << 16);
    lw_.x = (uint32_t)l0 | ((uint32_t)l1 << 16);
    lw_.y = (uint32_t)l2 | ((uint32_t)l3 << 16);
    *(uint2*)&cbh[(kk << 5) + (dq << 2)] = hw_;
    *(uint2*)&cbl[(kk << 5) + (dq << 2)] = lw_;
    float p = fmaf(v.x, v.x, fmaf(v.y, v.y, fmaf(v.z, v.z, v.w * v.w)));
    p += __shfl_xor(p, 1);
    p += __shfl_xor(p, 2);
    p += __shfl_xor(p, 4);
    if (dq == 0) c2l[kk] = p;
  }
  __syncthreads();

  // ---- x2 from recombined planes (consistent with MFMA's x-tilde) ----
  if (tid < 32){
    float s = 0.f;
    #pragma unroll
    for (int d = 0; d < 32; ++d){
      float vh = __uint_as_float(((uint32_t)xbh[(tid << 5) + d]) << 16);
      float vl = __uint_as_float(((uint32_t)xbl[(tid << 5) + d]) << 16);
      float v = vh + vl;
      s = fmaf(v, v, s);
    }
    x2l[tid] = s;
  }
  __syncthreads();

  const int lane = tid & 63;
  const int w    = tid >> 6;
  const int mh   = w >> 2;
  const int ng   = w & 3;
  const int l15  = lane & 15;
  const int kgrp = lane >> 4;

  bf16x8 Ah = *(const bf16x8*)&xbh[((mh * 16 + l15) << 5) + (kgrp << 3)];
  bf16x8 Al = *(const bf16x8*)&xbl[((mh * 16 + l15) << 5) + (kgrp << 3)];

  float x2r[4];
  #pragma unroll
  for (int j = 0; j < 4; ++j) x2r[j] = x2l[mh * 16 + (kgrp << 2) + j];

  const float tcl = fmaxf(temp[m], 1e-6f);
  const floatx4 z4 = (floatx4)(0.f);
  float bl[4], bg[4]; int bli[4], bgi[4];
  #pragma unroll
  for (int j = 0; j < 4; ++j){ bl[j] = -INFINITY; bg[j] = -INFINITY; bli[j] = 0; bgi[j] = 0; }

  #pragma unroll
  for (int t = 0; t < 4; ++t){
    const int nt = (ng << 2) + t;
    const int k_blk = (nt << 4) + l15;
    bf16x8 Bh = *(const bf16x8*)&cbh[(k_blk << 5) + (kgrp << 3)];
    bf16x8 Bl = *(const bf16x8*)&cbl[(k_blk << 5) + (kgrp << 3)];
    f32x4 acc = {0.f, 0.f, 0.f, 0.f};
    acc = __builtin_amdgcn_mfma_f32_16x16x32_bf16(Ah, Bh, acc, 0, 0, 0);
    acc = __builtin_amdgcn_mfma_f32_16x16x32_bf16(Ah, Bl, acc, 0, 0, 0);
    acc = __builtin_amdgcn_mfma_f32_16x16x32_bf16(Al, Bh, acc, 0, 0, 0);

    const float c2 = c2l[k_blk];
    const int k_g = k0 + k_blk;
    #pragma unroll
    for (int j = 0; j < 4; ++j){
      const int r_blk = mh * 16 + (kgrp << 2) + j;   // D: col=lane&15, row=(lane>>4)*4+reg
      const int row_g = rowbase + r_blk;
      float dist = x2r[j] + c2 - 2.0f * acc[j];
      float lgt = (-dist) * 0.015625f * tcl;
      logit_out[((size_t)row_g << 12) + k_g] = lgt;
      float lg = lgt + gumbel_from_e(((uint32_t)row_g << 12) + (uint32_t)k_g);
      if (lgt > bl[j]) { bl[j] = lgt; bli[j] = k_g; }
      if (lg  > bg[j]) { bg[j] = lg;  bgi[j] = k_g; }
    }

    if (USE_WS){
      // interleaved NT zero-fill slice t (full-line float4, never re-read:
      // bypass L2 so the fill stream doesn't evict logit lines)
      int s = tid + (t << 9);
      int r2 = s >> 6, w4 = s & 63;
      size_t f4 = (((size_t)(rowbase + r2)) << 10) + (k0 >> 2) + w4;
      __builtin_nontemporal_store(z4, (floatx4*)onehot + f4);
      __builtin_nontemporal_store(z4, (floatx4*)sample + f4);
    }
  }

  // ---- two-stage LDS argmax reduction (red overlays cbh/cbl/xb*; c2l/x2l dead) ----
  __syncthreads();
  #pragma unroll
  for (int j = 0; j < 4; ++j){
    int row = mh * 16 + (kgrp << 2) + j;
    int slot = (ng << 4) + l15;
    red[        row * 65 + slot] = bl[j];
    red[2080 +  row * 65 + slot] = __int_as_float(bli[j]);
    red[4160 +  row * 65 + slot] = bg[j];
    red[6240 +  row * 65 + slot] = __int_as_float(bgi[j]);
  }
  __syncthreads();
  if (tid < 64){
    const int r = tid & 31;
    const bool doG = (tid >= 32);
    const int off_v = doG ? 4160 : 0;
    const int off_i = doG ? 6240 : 2080;
    float bv = -INFINITY; int bi = 0;
    for (int g2 = 0; g2 < 64; ++g2){
      float v = red[off_v + r * 65 + g2];
      int  ix = __float_as_int(red[off_i + r * 65 + g2]);
      if (v > bv || (v == bv && ix < bi)){ bv = v; bi = ix; }
    }
    const int row_g = rowbase + r;
    if (USE_WS){
      *(float2*)&part_ws[((size_t)row_g << 6) + (kt << 2) + (doG ? 2 : 0)]
          = make_float2(bv, __int_as_float(bi));
    } else {
      float* part = sample + ((size_t)row_g << 12);
      part[(doG ? 32 : 0)  + kt] = bv;
      part[(doG ? 48 : 16) + kt] = __int_as_float(bi);
    }
  }

  if (!USE_WS){
    // fallback: R18-validated tail fill (plain stores)
    const float4 zz = make_float4(0.f, 0.f, 0.f, 0.f);
    #pragma unroll
    for (int i2 = 0; i2 < 4; ++i2){
      int s = tid + (i2 << 9);
      int r = s >> 6, w4 = s & 63;
      size_t f4 = (((size_t)(rowbase + r)) << 10) + (k0 >> 2) + w4;
      ((float4*)onehot)[f4] = zz;
      if (!(kt == 0 && w4 < 16))
        ((float4*)sample)[f4] = zz;
    }
  }
}

// Kernel 2: one wave per row (2048 blocks x 256). Reduce 16 partials, scatter.
template<bool USE_WS>
__global__ __launch_bounds__(256) void k_finalize(
    float* __restrict__ sample, float* __restrict__ code_out,
    float* __restrict__ onehot, const float* __restrict__ part_ws){
  const int tid = threadIdx.x;
  const int row = (blockIdx.x << 2) + (tid >> 6);
  const int lane = tid & 63;
  float* srow = sample + ((size_t)row << 12);
  float* orow = onehot + ((size_t)row << 12);

  const int g = (lane >> 4) & 1;
  const int l16 = lane & 15;
  float v; int ix;
  if (lane < 32){
    if (USE_WS){
      float2 p2 = *(const float2*)&part_ws[((size_t)row << 6) + (l16 << 2) + (g ? 2 : 0)];
      v = p2.x; ix = __float_as_int(p2.y);
    } else {
      v  = srow[g * 32 + l16];
      ix = __float_as_int(srow[g * 32 + 16 + l16]);
    }
  } else { v = -INFINITY; ix = 0x7fffffff; }
  #pragma unroll
  for (int off = 1; off < 16; off <<= 1){
    float ov = __shfl_xor(v, off, 16);
    int   oi = __shfl_xor(ix, off, 16);
    if (ov > v || (ov == v && oi < ix)){ v = ov; ix = oi; }
  }
  const int codei = __shfl(ix, 0, 64);   // L winner
  const int hard  = __shfl(ix, 16, 64);  // G winner

  if (USE_WS){
    if (lane == 0)      srow[hard]  = 1.0f;
    else if (lane == 1) orow[codei] = 1.0f;
    else if (lane == 2) code_out[row] = (float)codei;
  } else {
    if (lane < 16){
      float4 vs = make_float4(0.f, 0.f, 0.f, 0.f);
      if ((hard >> 2) == lane) ((float*)&vs)[hard & 3] = 1.0f;
      ((float4*)srow)[lane] = vs;
    } else if (lane == 16){
      if (hard >= 64) srow[hard] = 1.0f;
    } else if (lane == 17){
      orow[codei] = 1.0f;
    } else if (lane == 18){
      code_out[row] = (float)codei;
    }
  }
}

extern "C" void kernel_launch(void* const* d_in, const int* in_sizes, int n_in,
                              void* d_out, int out_size, void* d_ws, size_t ws_size,
                              hipStream_t stream) {
  const float* x    = (const float*)d_in[0];
  const float* cb   = (const float*)d_in[1];
  const float* temp = (const float*)d_in[2];
  float* out    = (float*)d_out;
  float* sample = out;                       // 33554432
  float* code   = out + 33554432;            // 8192
  float* onehot = code + 8192;               // 33554432
  float* logit  = onehot + 33554432;         // 33554432
  float* ws     = (float*)d_ws;

  const bool use_ws = ws_size >= (size_t)8192 * 64 * sizeof(float);
  if (use_ws){
    hipLaunchKernelGGL((k_logits<true>), dim3(4096), dim3(512), 0, stream,
                       x, cb, temp, logit, sample, onehot, ws);
    hipLaunchKernelGGL((k_finalize<true>), dim3(2048), dim3(256), 0, stream,
                       sample, code, onehot, ws);
  } else {
    hipLaunchKernelGGL((k_logits<false>), dim3(4096), dim3(512), 0, stream,
                       x, cb, temp, logit, sample, onehot, ws);
    hipLaunchKernelGGL((k_finalize<false>), dim3(2048), dim3(256), 0, stream,
                       sample, code, onehot, ws);
  }
}

// Round 26
// 111.807 us; speedup vs baseline: 1.1067x; 1.0006x over previous
//
#include <hip/hip_runtime.h>
#include <stdint.h>

// x: (8,128,16,16) f32 ; codebook: (4,4096,32) f32 ; temperature: (4,1,1,1)
// row = (n*4+m)*256 + hw, 8192 rows, K=4096, D=32
// outputs (flat f32): sample[33554432] code[8192] one_hot[33554432] logit[33554432]
//
// ROUND 26 = R25 (111.9us) + ONE change: logit stores also NON-TEMPORAL
// (the last plain bulk write stream, 134 MB; 64B/16-lane segments = full
// TCC lines, no partial-line risk). Completes the controlled NT A/B:
// NT-fill validated (R25, -7.2us); R10's NT regression was confounded
// (fp32 kernel, 2 blocks/CU).

typedef short bf16x8 __attribute__((ext_vector_type(8)));
typedef float f32x4  __attribute__((ext_vector_type(4)));
typedef float floatx4 __attribute__((ext_vector_type(4)));  // clang-native for NT builtin

__device__ __forceinline__ uint32_t rotl32(uint32_t x, uint32_t r){
  return (x << r) | (x >> (32u - r));
}

// JAX threefry2x32, key (0,42), partitionable scheme. Bits VALIDATED bit-exact
// (R2,4,6..); fast-log path VALIDATED (R11..R25).
__device__ __forceinline__ float gumbel_from_e(uint32_t e){
  uint32_t x0 = 0u, x1 = e;
  const uint32_t ks0 = 0u, ks1 = 42u, ks2 = 0x1BD11BF0u;
  x0 += ks0; x1 += ks1;
#define TFR4(a,b,c,d2) \
  x0 += x1; x1 = rotl32(x1,(a)); x1 ^= x0; \
  x0 += x1; x1 = rotl32(x1,(b)); x1 ^= x0; \
  x0 += x1; x1 = rotl32(x1,(c)); x1 ^= x0; \
  x0 += x1; x1 = rotl32(x1,(d2)); x1 ^= x0;
  TFR4(13,15,26,6)  x0 += ks1; x1 += ks2 + 1u;
  TFR4(17,29,16,24) x0 += ks2; x1 += ks0 + 2u;
  TFR4(13,15,26,6)  x0 += ks0; x1 += ks1 + 3u;
  TFR4(17,29,16,24) x0 += ks1; x1 += ks2 + 4u;
  TFR4(13,15,26,6)  x0 += ks2; x1 += ks0 + 5u;
#undef TFR4
  uint32_t bits = x0 ^ x1;
  float u = __uint_as_float((bits >> 9) | 0x3F800000u) - 1.0f;
  u = fminf(fmaxf(u, 1.1920929e-07f), __uint_as_float(0x3F7FFFFEu));
  const float LN2 = 0.69314718055994531f;
  float v = -LN2 * __log2f(u);
  return -LN2 * __log2f(v);
}

// Truncating bf16 split: v ~= hi + lo, |v-(hi+lo)| <= 2^-16 |v|.
__device__ __forceinline__ void split_bf16(float v, unsigned short& hi, unsigned short& lo){
  uint32_t b = __float_as_uint(v);
  hi = (unsigned short)(b >> 16);
  float r = v - __uint_as_float(b & 0xFFFF0000u);
  lo = (unsigned short)(__float_as_uint(r) >> 16);
}

// Kernel 1: grid 4096 = m(4) x rowtile(64) x ktile(16); block 512 thr (8 waves),
// 32 rows x 256 k. bf16x3 MFMA GEMM (R17 layouts), ws partials (R18),
// interleaved NT zero-fill (R25), NT logit stores (R26), 38KB LDS (R23),
// VGPR capped to 64 (R24).
template<bool USE_WS>
__global__ __launch_bounds__(512, 8) void k_logits(
    const float* __restrict__ x, const float* __restrict__ cb,
    const float* __restrict__ temp, float* __restrict__ logit_out,
    float* __restrict__ sample, float* __restrict__ onehot,
    float* __restrict__ part_ws){
  __shared__ __align__(16) char smem[38016];
  unsigned short* cbh = (unsigned short*)smem;        // 256x32 bf16 hi   [0,16384)
  unsigned short* cbl = cbh + 8192;                   // 256x32 bf16 lo   [16384,32768)
  unsigned short* xbh = cbl + 8192;                   // 32x32 bf16 hi    [32768,34816)
  unsigned short* xbl = xbh + 1024;                   // 32x32 bf16 lo    [34816,36864)
  float* c2l = (float*)(xbl + 1024);                  // 256 f32          [36864,37888)
  float* x2l = c2l + 256;                             // 32 f32           [37888,38016)
  float* red = (float*)smem;                          // argmax scratch overlays 33280 B

  const int tid = threadIdx.x;
  const int b = blockIdx.x;
  const int kt = b & 15;
  const int rt = (b >> 4) & 63;
  const int m  = b >> 10;
  const int n  = rt >> 3;
  const int hw0 = (rt & 7) << 5;
  const int k0 = kt << 8;
  const int rowbase = ((n << 2) + m) * 256 + hw0;

  // ---- stage x tile (32 rows x 32 d) as bf16 hi/lo planes ----
  const float* xm = x + ((n * 128 + m * 32) * 256 + hw0);
  #pragma unroll
  for (int i = 0; i < 2; ++i){
    int idx = tid + (i << 9);
    int d = idx >> 5, r = idx & 31;
    float v = xm[(d << 8) + r];
    unsigned short h, l;
    split_bf16(v, h, l);
    xbh[(r << 5) + d] = h;
    xbl[(r << 5) + d] = l;
  }
  // ---- stage codebook tile: bf16 hi/lo + shuffle-tree c2 ----
  const float4* cb4 = (const float4*)(cb + (m * 131072 + k0 * 32));
  #pragma unroll
  for (int i = 0; i < 4; ++i){
    int f = tid + (i << 9);
    float4 v = cb4[f];
    int kk = f >> 3, dq = f & 7;
    unsigned short h0,h1,h2,h3,l0,l1,l2,l3;
    split_bf16(v.x, h0, l0); split_bf16(v.y, h1, l1);
    split_bf16(v.z, h2, l2); split_bf16(v.w, h3, l3);
    uint2 hw_, lw_;
    hw_.x = (uint32_t)h0 | ((uint32_t)h1 << 16);
    hw_.y = (uint32_t)h2 | ((uint32_t)h3 << 16);
    lw_.x = (uint32_t)l0 | ((uint32_t)l1 << 16);
    lw_.y = (uint32_t)l2 | ((uint32_t)l3 << 16);
    *(uint2*)&cbh[(kk << 5) + (dq << 2)] = hw_;
    *(uint2*)&cbl[(kk << 5) + (dq << 2)] = lw_;
    float p = fmaf(v.x, v.x, fmaf(v.y, v.y, fmaf(v.z, v.z, v.w * v.w)));
    p += __shfl_xor(p, 1);
    p += __shfl_xor(p, 2);
    p += __shfl_xor(p, 4);
    if (dq == 0) c2l[kk] = p;
  }
  __syncthreads();

  // ---- x2 from recombined planes (consistent with MFMA's x-tilde) ----
  if (tid < 32){
    float s = 0.f;
    #pragma unroll
    for (int d = 0; d < 32; ++d){
      float vh = __uint_as_float(((uint32_t)xbh[(tid << 5) + d]) << 16);
      float vl = __uint_as_float(((uint32_t)xbl[(tid << 5) + d]) << 16);
      float v = vh + vl;
      s = fmaf(v, v, s);
    }
    x2l[tid] = s;
  }
  __syncthreads();

  const int lane = tid & 63;
  const int w    = tid >> 6;
  const int mh   = w >> 2;
  const int ng   = w & 3;
  const int l15  = lane & 15;
  const int kgrp = lane >> 4;

  bf16x8 Ah = *(const bf16x8*)&xbh[((mh * 16 + l15) << 5) + (kgrp << 3)];
  bf16x8 Al = *(const bf16x8*)&xbl[((mh * 16 + l15) << 5) + (kgrp << 3)];

  float x2r[4];
  #pragma unroll
  for (int j = 0; j < 4; ++j) x2r[j] = x2l[mh * 16 + (kgrp << 2) + j];

  const float tcl = fmaxf(temp[m], 1e-6f);
  const floatx4 z4 = (floatx4)(0.f);
  float bl[4], bg[4]; int bli[4], bgi[4];
  #pragma unroll
  for (int j = 0; j < 4; ++j){ bl[j] = -INFINITY; bg[j] = -INFINITY; bli[j] = 0; bgi[j] = 0; }

  #pragma unroll
  for (int t = 0; t < 4; ++t){
    const int nt = (ng << 2) + t;
    const int k_blk = (nt << 4) + l15;
    bf16x8 Bh = *(const bf16x8*)&cbh[(k_blk << 5) + (kgrp << 3)];
    bf16x8 Bl = *(const bf16x8*)&cbl[(k_blk << 5) + (kgrp << 3)];
    f32x4 acc = {0.f, 0.f, 0.f, 0.f};
    acc = __builtin_amdgcn_mfma_f32_16x16x32_bf16(Ah, Bh, acc, 0, 0, 0);
    acc = __builtin_amdgcn_mfma_f32_16x16x32_bf16(Ah, Bl, acc, 0, 0, 0);
    acc = __builtin_amdgcn_mfma_f32_16x16x32_bf16(Al, Bh, acc, 0, 0, 0);

    const float c2 = c2l[k_blk];
    const int k_g = k0 + k_blk;
    #pragma unroll
    for (int j = 0; j < 4; ++j){
      const int r_blk = mh * 16 + (kgrp << 2) + j;   // D: col=lane&15, row=(lane>>4)*4+reg
      const int row_g = rowbase + r_blk;
      float dist = x2r[j] + c2 - 2.0f * acc[j];
      float lgt = (-dist) * 0.015625f * tcl;
      __builtin_nontemporal_store(lgt, &logit_out[((size_t)row_g << 12) + k_g]);
      float lg = lgt + gumbel_from_e(((uint32_t)row_g << 12) + (uint32_t)k_g);
      if (lgt > bl[j]) { bl[j] = lgt; bli[j] = k_g; }
      if (lg  > bg[j]) { bg[j] = lg;  bgi[j] = k_g; }
    }

    if (USE_WS){
      // interleaved NT zero-fill slice t
      int s = tid + (t << 9);
      int r2 = s >> 6, w4 = s & 63;
      size_t f4 = (((size_t)(rowbase + r2)) << 10) + (k0 >> 2) + w4;
      __builtin_nontemporal_store(z4, (floatx4*)onehot + f4);
      __builtin_nontemporal_store(z4, (floatx4*)sample + f4);
    }
  }

  // ---- two-stage LDS argmax reduction (red overlays cbh/cbl/xb*; c2l/x2l dead) ----
  __syncthreads();
  #pragma unroll
  for (int j = 0; j < 4; ++j){
    int row = mh * 16 + (kgrp << 2) + j;
    int slot = (ng << 4) + l15;
    red[        row * 65 + slot] = bl[j];
    red[2080 +  row * 65 + slot] = __int_as_float(bli[j]);
    red[4160 +  row * 65 + slot] = bg[j];
    red[6240 +  row * 65 + slot] = __int_as_float(bgi[j]);
  }
  __syncthreads();
  if (tid < 64){
    const int r = tid & 31;
    const bool doG = (tid >= 32);
    const int off_v = doG ? 4160 : 0;
    const int off_i = doG ? 6240 : 2080;
    float bv = -INFINITY; int bi = 0;
    for (int g2 = 0; g2 < 64; ++g2){
      float v = red[off_v + r * 65 + g2];
      int  ix = __float_as_int(red[off_i + r * 65 + g2]);
      if (v > bv || (v == bv && ix < bi)){ bv = v; bi = ix; }
    }
    const int row_g = rowbase + r;
    if (USE_WS){
      *(float2*)&part_ws[((size_t)row_g << 6) + (kt << 2) + (doG ? 2 : 0)]
          = make_float2(bv, __int_as_float(bi));
    } else {
      float* part = sample + ((size_t)row_g << 12);
      part[(doG ? 32 : 0)  + kt] = bv;
      part[(doG ? 48 : 16) + kt] = __int_as_float(bi);
    }
  }

  if (!USE_WS){
    // fallback: R18-validated tail fill (plain stores)
    const float4 zz = make_float4(0.f, 0.f, 0.f, 0.f);
    #pragma unroll
    for (int i2 = 0; i2 < 4; ++i2){
      int s = tid + (i2 << 9);
      int r = s >> 6, w4 = s & 63;
      size_t f4 = (((size_t)(rowbase + r)) << 10) + (k0 >> 2) + w4;
      ((float4*)onehot)[f4] = zz;
      if (!(kt == 0 && w4 < 16))
        ((float4*)sample)[f4] = zz;
    }
  }
}

// Kernel 2: one wave per row (2048 blocks x 256). Reduce 16 partials, scatter.
template<bool USE_WS>
__global__ __launch_bounds__(256) void k_finalize(
    float* __restrict__ sample, float* __restrict__ code_out,
    float* __restrict__ onehot, const float* __restrict__ part_ws){
  const int tid = threadIdx.x;
  const int row = (blockIdx.x << 2) + (tid >> 6);
  const int lane = tid & 63;
  float* srow = sample + ((size_t)row << 12);
  float* orow = onehot + ((size_t)row << 12);

  const int g = (lane >> 4) & 1;
  const int l16 = lane & 15;
  float v; int ix;
  if (lane < 32){
    if (USE_WS){
      float2 p2 = *(const float2*)&part_ws[((size_t)row << 6) + (l16 << 2) + (g ? 2 : 0)];
      v = p2.x; ix = __float_as_int(p2.y);
    } else {
      v  = srow[g * 32 + l16];
      ix = __float_as_int(srow[g * 32 + 16 + l16]);
    }
  } else { v = -INFINITY; ix = 0x7fffffff; }
  #pragma unroll
  for (int off = 1; off < 16; off <<= 1){
    float ov = __shfl_xor(v, off, 16);
    int   oi = __shfl_xor(ix, off, 16);
    if (ov > v || (ov == v && oi < ix)){ v = ov; ix = oi; }
  }
  const int codei = __shfl(ix, 0, 64);   // L winner
  const int hard  = __shfl(ix, 16, 64);  // G winner

  if (USE_WS){
    if (lane == 0)      srow[hard]  = 1.0f;
    else if (lane == 1) orow[codei] = 1.0f;
    else if (lane == 2) code_out[row] = (float)codei;
  } else {
    if (lane < 16){
      float4 vs = make_float4(0.f, 0.f, 0.f, 0.f);
      if ((hard >> 2) == lane) ((float*)&vs)[hard & 3] = 1.0f;
      ((float4*)srow)[lane] = vs;
    } else if (lane == 16){
      if (hard >= 64) srow[hard] = 1.0f;
    } else if (lane == 17){
      orow[codei] = 1.0f;
    } else if (lane == 18){
      code_out[row] = (float)codei;
    }
  }
}

extern "C" void kernel_launch(void* const* d_in, const int* in_sizes, int n_in,
                              void* d_out, int out_size, void* d_ws, size_t ws_size,
                              hipStream_t stream) {
  const float* x    = (const float*)d_in[0];
  const float* cb   = (const float*)d_in[1];
  const float* temp = (const float*)d_in[2];
  float* out    = (float*)d_out;
  float* sample = out;                       // 33554432
  float* code   = out + 33554432;            // 8192
  float* onehot = code + 8192;               // 33554432
  float* logit  = onehot + 33554432;         // 33554432
  float* ws     = (float*)d_ws;

  const bool use_ws = ws_size >= (size_t)8192 * 64 * sizeof(float);
  if (use_ws){
    hipLaunchKernelGGL((k_logits<true>), dim3(4096), dim3(512), 0, stream,
                       x, cb, temp, logit, sample, onehot, ws);
    hipLaunchKernelGGL((k_finalize<true>), dim3(2048), dim3(256), 0, stream,
                       sample, code, onehot, ws);
  } else {
    hipLaunchKernelGGL((k_logits<false>), dim3(4096), dim3(512), 0, stream,
                       x, cb, temp, logit, sample, onehot, ws);
    hipLaunchKernelGGL((k_finalize<false>), dim3(2048), dim3(256), 0, stream,
                       sample, code, onehot, ws);
  }
}